// Round 6
// baseline (104.209 us; speedup 1.0000x reference)
//
#include <hip/hip_runtime.h>

#define NB_BS   2048
#define NB_NINP 512
#define NB_NHID 512
#define NB_K    16
#define NB_T    8
#define NB_M    32
#define NB_C    768   // T * 3 * M
#define H_OUT_ELEMS (NB_BS * NB_NHID)   // 1048576

// ---------------------------------------------------------------------------
// Kernel 1: gi'[b][c] = sum_i x[b][i]*Wih[c][i] + bih[c] + (gate<2 ? bhh[c] : 0)
// 32x64 tile, BK=64, 256 threads, 2x4 micro-tile. Grid (64,12) = 768 blocks
// = 3 blocks/CU = 3 waves/SIMD (round-5 ran 2 and was latency-bound at ~41us
// vs a 10.2us VALU floor). BK=64 halves barrier count (8 slabs).
// Inner reads: av b64 (16 unique addrs, 2-way = free) + wv b128 (4 unique).
// ---------------------------------------------------------------------------
__global__ __launch_bounds__(256, 3)
void k1_gemm_gi(const float* __restrict__ x, const float* __restrict__ Wih,
                const float* __restrict__ bih, const float* __restrict__ bhh,
                float* __restrict__ gi)
{
    __shared__ __align__(16) float As[64][34];    // [k][row]  8.7 KB
    __shared__ __align__(16) float Bs[64][68];    // [k][col] 17.4 KB

    const int tid  = threadIdx.x;
    const int row0 = blockIdx.x * 32;     // 64 row blocks
    const int col0 = blockIdx.y * 64;     // 12 col blocks
    const int wave = tid >> 6, lane = tid & 63;
    const int rg   = lane >> 2;           // 0..15 -> rows rg*2, rg*2+1
    const int cg   = lane & 3;            // 0..3
    const int wc0  = wave * 16 + cg * 4;  // col within tile

    // A staging: 2 rounds of 256 float4 (32 rows x 64 k)
    const int ar0 = tid >> 4,           ak0 = (tid & 15) * 4;
    const int ar1 = (tid + 256) >> 4,   ak1 = ((tid + 256) & 15) * 4;
    // B staging: 4 rounds of 256 float4 (64 cols x 64 k)
    int bc[4], bk[4];
    #pragma unroll
    for (int l = 0; l < 4; ++l) {
        const int q = l * 256 + tid;
        bc[l] = q >> 4; bk[l] = (q & 15) * 4;
    }

    float4 a0 = *(const float4*)&x[(size_t)(row0 + ar0) * NB_NINP + ak0];
    float4 a1 = *(const float4*)&x[(size_t)(row0 + ar1) * NB_NINP + ak1];
    float4 bfr[4];
    #pragma unroll
    for (int l = 0; l < 4; ++l)
        bfr[l] = *(const float4*)&Wih[(size_t)(col0 + bc[l]) * NB_NINP + bk[l]];

    float acc[2][4];
    #pragma unroll
    for (int i = 0; i < 2; ++i)
        #pragma unroll
        for (int e = 0; e < 4; ++e) acc[i][e] = 0.f;

    for (int kb = 0; kb < NB_NINP; kb += 64) {
        __syncthreads();
        As[ak0+0][ar0]=a0.x; As[ak0+1][ar0]=a0.y; As[ak0+2][ar0]=a0.z; As[ak0+3][ar0]=a0.w;
        As[ak1+0][ar1]=a1.x; As[ak1+1][ar1]=a1.y; As[ak1+2][ar1]=a1.z; As[ak1+3][ar1]=a1.w;
        #pragma unroll
        for (int l = 0; l < 4; ++l) {
            Bs[bk[l]+0][bc[l]]=bfr[l].x; Bs[bk[l]+1][bc[l]]=bfr[l].y;
            Bs[bk[l]+2][bc[l]]=bfr[l].z; Bs[bk[l]+3][bc[l]]=bfr[l].w;
        }
        __syncthreads();
        if (kb + 64 < NB_NINP) {    // prefetch next K-slab into regs
            a0 = *(const float4*)&x[(size_t)(row0 + ar0) * NB_NINP + kb + 64 + ak0];
            a1 = *(const float4*)&x[(size_t)(row0 + ar1) * NB_NINP + kb + 64 + ak1];
            #pragma unroll
            for (int l = 0; l < 4; ++l)
                bfr[l] = *(const float4*)&Wih[(size_t)(col0 + bc[l]) * NB_NINP + kb + 64 + bk[l]];
        }
        #pragma unroll 16
        for (int kk = 0; kk < 64; ++kk) {
            const float2 av = *(const float2*)&As[kk][rg * 2];
            const float4 wv = *(const float4*)&Bs[kk][wc0];
            const float avv[2] = {av.x, av.y};
            const float wvv[4] = {wv.x, wv.y, wv.z, wv.w};
            #pragma unroll
            for (int i = 0; i < 2; ++i)
                #pragma unroll
                for (int e = 0; e < 4; ++e)
                    acc[i][e] = fmaf(avv[i], wvv[e], acc[i][e]);
        }
    }

    float bias[4];
    #pragma unroll
    for (int e = 0; e < 4; ++e) {
        const int c = col0 + wc0 + e;
        bias[e] = bih[c] + ((c % 96) < 64 ? bhh[c] : 0.f);
    }
    #pragma unroll
    for (int i = 0; i < 2; ++i) {
        float4 o;
        o.x = acc[i][0] + bias[0]; o.y = acc[i][1] + bias[1];
        o.z = acc[i][2] + bias[2]; o.w = acc[i][3] + bias[3];
        *(float4*)&gi[(size_t)(row0 + rg * 2 + i) * NB_C + col0 + wc0] = o;
    }
}

// ---------------------------------------------------------------------------
// Kernel 2: fused gh-GEMM + GRU + write-key logits + gumbel-argmax + gather.
// 256 blocks x 1024 threads (16 waves = 4 waves/SIMD), waves_per_eu(4,4)
// pins VGPR budget at 128 (spill guard, rounds 2-5 lesson).
// NEW wave mapping: wave = (bl, tq) owns ALL 16 k's of b for template-quad
// tq*4..tq*4+3; lane = (m_, half); lane's 2 templates t = tq*4+half*2+u.
// acc[16][6] (96 regs) -> the whole Whh half is streamed ONCE per wave:
// P-LDS traffic 3MB -> 768KB per CU (was the round-5 LDS-pipe bottleneck),
// and the logit shfl-reduce drops 24 -> 10 ops per k (2 logits per lane).
// The 8 logits per (b,k) straddle 2 waves -> 4KB LDS exchange + 1 sync;
// both waves redo argmax redundantly (identical inputs -> identical result).
// P2 slot is XOR-swizzled by mm (staging writes 2-way, reads perm = free).
// ---------------------------------------------------------------------------
__global__ __launch_bounds__(1024)
__attribute__((amdgpu_waves_per_eu(4, 4)))
void k2_fused(const float* __restrict__ h,      const float* __restrict__ Whh,
              const float* __restrict__ bhh,    const float* __restrict__ wread,
              const float* __restrict__ wwrite, const float* __restrict__ gumb,
              const float* __restrict__ gi,     float* __restrict__ out)
{
    __shared__ __align__(16) float P2[2][3][32][128];  // 96 KB  Whh, float2/lane
    __shared__ __align__(16) float WWT2[2][16][128];   // 16 KB  w_write, float2/lane
    __shared__ __align__(16) float WR[512];            //  2 KB  w_read [m][f]
    __shared__ __align__(16) float HT[8][32][20];      // 20 KB  [bl][m][k]
    __shared__ __align__(16) float HR2T[8][16][20];    // 10 KB  [bl][f][k]
    __shared__ __align__(16) float LG[8][16][8];       //  4 KB  [bl][k][t]

    const int tid  = threadIdx.x;
    const int wave = tid >> 6, lane = tid & 63;
    const int bl   = wave >> 1, tq = wave & 1;
    const int b    = blockIdx.x * 8 + bl;
    const int m_   = lane & 31, half = lane >> 5;

    // ---- stage Whh: value (t,gc,mout,mm) -> reading lane hf*32+mout, float2
    //      component u, at slot (lane ^ mm)
    for (int i = tid; i < 24576; i += 1024) {
        const int c = i >> 5, mm = i & 31;       // Whh flat [c][mm], c=t*96+gc*32+mout
        const int t = c / 96, rem = c - t * 96;
        const int gc = rem >> 5, mout = rem & 31;
        const int slot = (((t >> 1) & 1) * 32 + mout) ^ mm;
        P2[t >> 2][gc][mm][slot * 2 + (t & 1)] = Whh[i];
    }
    for (int i = tid; i < 4096; i += 1024) {     // wwrite flat [t][m][f]
        const int t = i >> 9, mo = (i >> 4) & 31, f = i & 15;
        WWT2[t >> 2][f][(((t >> 1) & 1) * 32 + mo) * 2 + (t & 1)] = wwrite[i];
    }
    if (tid < 512) WR[tid] = wread[tid];
    #pragma unroll
    for (int e = 0; e < 4; ++e) {                // h row transposed: HT[m][k]
        const int idx = tq * 256 + e * 64 + lane;
        HT[bl][idx & 31][idx >> 5] = h[(size_t)b * NB_NHID + idx];
    }
    __syncthreads();

    // ---- h_read for this wave's 8 k's: lane owns (kq, f-pair)
    {
        const int kq = tq * 8 + (lane >> 3);
        const int f0 = (lane & 7) * 2;
        float s0 = 0.f, s1 = 0.f;
        #pragma unroll 8
        for (int mm = 0; mm < 32; ++mm) {
            const float hv = HT[bl][mm][kq];
            s0 = fmaf(hv, WR[mm * 16 + f0], s0);
            s1 = fmaf(hv, WR[mm * 16 + f0 + 1], s1);
        }
        HR2T[bl][f0    ][kq] = s0;
        HR2T[bl][f0 + 1][kq] = s1;
    }

    // ---- gh GEMM: acc[k][j], j = u*3+gc; single streaming pass over Whh-half
    float acc[16][6];
    #pragma unroll
    for (int k = 0; k < 16; ++k)
        #pragma unroll
        for (int j = 0; j < 6; ++j) acc[k][j] = 0.f;

    #pragma unroll 1
    for (int mm = 0; mm < 32; ++mm) {
        const int sl2 = (lane ^ mm) * 2;
        const float2 w0 = *(const float2*)&P2[tq][0][mm][sl2];
        const float2 w1 = *(const float2*)&P2[tq][1][mm][sl2];
        const float2 w2 = *(const float2*)&P2[tq][2][mm][sl2];
        #pragma unroll
        for (int q = 0; q < 4; ++q) {
            const float4 hv = *(const float4*)&HT[bl][mm][q * 4];   // broadcast
            const float hr[4] = {hv.x, hv.y, hv.z, hv.w};
            #pragma unroll
            for (int r = 0; r < 4; ++r) {
                const int k = q * 4 + r;
                acc[k][0] = fmaf(hr[r], w0.x, acc[k][0]);
                acc[k][1] = fmaf(hr[r], w1.x, acc[k][1]);
                acc[k][2] = fmaf(hr[r], w2.x, acc[k][2]);
                acc[k][3] = fmaf(hr[r], w0.y, acc[k][3]);
                acc[k][4] = fmaf(hr[r], w1.y, acc[k][4]);
                acc[k][5] = fmaf(hr[r], w2.y, acc[k][5]);
            }
        }
    }
    __syncthreads();   // other wave's HR2T half now visible

    // ---- per-lane gi' (bih+bhh_{r,z} folded by k1) and bhh_n, 2 templates
    float gi_r[2][3], bhn[2];
    #pragma unroll
    for (int u = 0; u < 2; ++u) {
        const int t = tq * 4 + half * 2 + u;
        #pragma unroll
        for (int gc = 0; gc < 3; ++gc)
            gi_r[u][gc] = gi[(size_t)b * NB_C + t * 96 + gc * 32 + m_];
        bhn[u] = bhh[t * 96 + 64 + m_];
    }

    float hn[16][2];
    #pragma unroll
    for (int q = 0; q < 4; ++q) {
        // write-key dot ww[r][u] = sum_f w_write[t][m_][f] * h_read[k][f]
        float ww[4][2];
        #pragma unroll
        for (int r = 0; r < 4; ++r) { ww[r][0] = 0.f; ww[r][1] = 0.f; }
        #pragma unroll 4
        for (int f = 0; f < 16; ++f) {
            const float2 wt = *(const float2*)&WWT2[tq][f][lane * 2];
            const float4 hk = *(const float4*)&HR2T[bl][f][q * 4];  // broadcast
            const float hh[4] = {hk.x, hk.y, hk.z, hk.w};
            #pragma unroll
            for (int r = 0; r < 4; ++r) {
                ww[r][0] = fmaf(hh[r], wt.x, ww[r][0]);
                ww[r][1] = fmaf(hh[r], wt.y, ww[r][1]);
            }
        }
        #pragma unroll
        for (int r = 0; r < 4; ++r) {
            const int k = q * 4 + r;
            const float h2v = HT[bl][m_][k];
            float lg2[2];
            #pragma unroll
            for (int u = 0; u < 2; ++u) {
                const float xr = gi_r[u][0] + acc[k][u*3+0];
                const float xz = gi_r[u][1] + acc[k][u*3+1];
                const float gn = bhn[u]     + acc[k][u*3+2];
                const float rg = 1.f / (1.f + __expf(-xr));
                const float zg = 1.f / (1.f + __expf(-xz));
                const float xn = gi_r[u][2] + rg * gn;
                const float e2 = __expf(2.f * xn);
                const float tn = 1.f - 2.f / (e2 + 1.f);   // tanh
                const float hv2 = (1.f - zg) * tn + zg * h2v;
                hn[k][u] = hv2;
                float part = hv2 * ww[r][u];               // logit partial
                part += __shfl_xor(part, 1, 64);
                part += __shfl_xor(part, 2, 64);
                part += __shfl_xor(part, 4, 64);
                part += __shfl_xor(part, 8, 64);
                part += __shfl_xor(part, 16, 64);
                lg2[u] = part;
            }
            if (m_ == 0) {                                 // 2 lanes write 4 t's
                LG[bl][k][tq * 4 + half * 2 + 0] = lg2[0];
                LG[bl][k][tq * 4 + half * 2 + 1] = lg2[1];
            }
        }
    }
    __syncthreads();   // all 8 logits per (b,k) visible

    // ---- final: gumbel-argmax (redundant in both waves), gather + one-hot
    #pragma unroll
    for (int k = 0; k < 16; ++k) {
        const float4 l0 = *(const float4*)&LG[bl][k][0];   // broadcast
        const float4 l1 = *(const float4*)&LG[bl][k][4];
        const float* gp = gumb + ((size_t)b * NB_K + k) * NB_T;
        const float4 g0 = *(const float4*)gp;
        const float4 g1 = *(const float4*)(gp + 4);
        const float s[8] = {l0.x+g0.x, l0.y+g0.y, l0.z+g0.z, l0.w+g0.w,
                            l1.x+g1.x, l1.y+g1.y, l1.z+g1.z, l1.w+g1.w};
        float best = s[0]; int bt = 0;
        #pragma unroll
        for (int t2 = 1; t2 < 8; ++t2)
            if (s[t2] > best) { best = s[t2]; bt = t2; }   // first-max argmax
        const float hsel = (bt & 1) ? hn[k][1] : hn[k][0];
        if ((bt >> 2) == tq && ((bt >> 1) & 1) == half)
            out[(size_t)b * NB_NHID + k * 32 + m_] = hsel;
        if (tq == 0 && lane < 8)
            out[H_OUT_ELEMS + ((size_t)b * NB_K + k) * NB_T + lane] =
                (lane == bt) ? 1.f : 0.f;
    }
}

extern "C" void kernel_launch(void* const* d_in, const int* in_sizes, int n_in,
                              void* d_out, int out_size, void* d_ws, size_t ws_size,
                              hipStream_t stream) {
    const float* x      = (const float*)d_in[0];
    const float* h      = (const float*)d_in[1];
    const float* Wih    = (const float*)d_in[2];
    const float* Whh    = (const float*)d_in[3];
    const float* bih    = (const float*)d_in[4];
    const float* bhh    = (const float*)d_in[5];
    const float* wread  = (const float*)d_in[6];
    const float* wwrite = (const float*)d_in[7];
    const float* gumb   = (const float*)d_in[8];
    float* out = (float*)d_out;
    float* gi  = (float*)d_ws;   // 2048*768*4 = 6 MB scratch

    k1_gemm_gi<<<dim3(64, 12), 256, 0, stream>>>(x, Wih, bih, bhh, gi);
    k2_fused<<<dim3(256), 1024, 0, stream>>>(h, Whh, bhh, wread, wwrite,
                                             gumb, gi, out);
}

// Round 7
// 92.116 us; speedup vs baseline: 1.1313x; 1.1313x over previous
//
#include <hip/hip_runtime.h>

#define NB_BS   2048
#define NB_NINP 512
#define NB_NHID 512
#define NB_K    16
#define NB_T    8
#define NB_M    32
#define NB_C    768   // T * 3 * M
#define H_OUT_ELEMS (NB_BS * NB_NHID)   // 1048576

// ---------------------------------------------------------------------------
// Kernel 1: gi'[b][c] = sum_i x[b][i]*Wih[c][i] + bih[c] + (gate<2 ? bhh[c] : 0)
// 64x96 tile, 512 threads, INTRA-BLOCK K-SPLIT: waves 0-3 accumulate K=0..255,
// waves 4-7 K=256..511 into private acc; combined through LDS at the end.
// Grid (32,8) = 256 blocks = 1/CU balanced, 8 waves = 2 waves/SIMD.
// Micro-tile 4x6: per kk, av = b128 at 4 addrs/wave (broadcast-cheap),
// wv = 3x b64 at 16 addrs (2-way, free) -> ~22 LDS cyc per 48 FMA cyc.
// (r6 lesson: k1 is LDS-pipe-bound per CU; only fma:byte ratio helps.)
// ---------------------------------------------------------------------------
__global__ __launch_bounds__(512, 2)
void k1_gemm_gi(const float* __restrict__ x, const float* __restrict__ Wih,
                const float* __restrict__ bih, const float* __restrict__ bhh,
                float* __restrict__ gi)
{
    __shared__ __align__(16) float As[2][32][68];    // [kg][k][row] 17.4 KB
    __shared__ __align__(16) float Bs[2][32][100];   // [kg][k][col] 25.6 KB
    __shared__ float ACCX[256][25];                  // 25.6 KB (25: odd stride)

    const int tid  = threadIdx.x;
    const int kg   = tid >> 8;            // K-group: 0 -> k<256, 1 -> k>=256
    const int ttid = tid & 255;
    const int row0 = blockIdx.x * 64;
    const int col0 = blockIdx.y * 96;
    const int rg   = ttid >> 4;           // 0..15 -> rows rg*4..+3
    const int cg   = ttid & 15;           // 0..15 -> cols cg*6..+5
    const int kb0  = kg * 256;

    // A staging: 2 float4/thread (64 rows x 8 k-quads)
    const int ar0 = ttid >> 3, akq = (ttid & 7) * 4, ar1 = ar0 + 32;
    // B staging: 3 float4/thread (96 cols x 8 k-quads)
    int bc[3], bkq[3];
    #pragma unroll
    for (int l = 0; l < 3; ++l) {
        const int q = l * 256 + ttid;
        bc[l] = q >> 3; bkq[l] = (q & 7) * 4;
    }

    float4 a0 = *(const float4*)&x[(size_t)(row0 + ar0) * NB_NINP + kb0 + akq];
    float4 a1 = *(const float4*)&x[(size_t)(row0 + ar1) * NB_NINP + kb0 + akq];
    float4 bf[3];
    #pragma unroll
    for (int l = 0; l < 3; ++l)
        bf[l] = *(const float4*)&Wih[(size_t)(col0 + bc[l]) * NB_NINP + kb0 + bkq[l]];

    float acc[4][6];
    #pragma unroll
    for (int i = 0; i < 4; ++i)
        #pragma unroll
        for (int e = 0; e < 6; ++e) acc[i][e] = 0.f;

    for (int slab = 0; slab < 8; ++slab) {
        __syncthreads();
        As[kg][akq+0][ar0]=a0.x; As[kg][akq+1][ar0]=a0.y;
        As[kg][akq+2][ar0]=a0.z; As[kg][akq+3][ar0]=a0.w;
        As[kg][akq+0][ar1]=a1.x; As[kg][akq+1][ar1]=a1.y;
        As[kg][akq+2][ar1]=a1.z; As[kg][akq+3][ar1]=a1.w;
        #pragma unroll
        for (int l = 0; l < 3; ++l) {
            Bs[kg][bkq[l]+0][bc[l]]=bf[l].x; Bs[kg][bkq[l]+1][bc[l]]=bf[l].y;
            Bs[kg][bkq[l]+2][bc[l]]=bf[l].z; Bs[kg][bkq[l]+3][bc[l]]=bf[l].w;
        }
        __syncthreads();
        if (slab < 7) {   // prefetch next slab of this K-half
            const int kb = kb0 + (slab + 1) * 32;
            a0 = *(const float4*)&x[(size_t)(row0 + ar0) * NB_NINP + kb + akq];
            a1 = *(const float4*)&x[(size_t)(row0 + ar1) * NB_NINP + kb + akq];
            #pragma unroll
            for (int l = 0; l < 3; ++l)
                bf[l] = *(const float4*)&Wih[(size_t)(col0 + bc[l]) * NB_NINP + kb + bkq[l]];
        }
        #pragma unroll
        for (int kk = 0; kk < 32; ++kk) {
            const float4 av = *(const float4*)&As[kg][kk][rg * 4];
            const float2 w0 = *(const float2*)&Bs[kg][kk][cg * 6];
            const float2 w1 = *(const float2*)&Bs[kg][kk][cg * 6 + 2];
            const float2 w2 = *(const float2*)&Bs[kg][kk][cg * 6 + 4];
            const float avv[4] = {av.x, av.y, av.z, av.w};
            const float wvv[6] = {w0.x, w0.y, w1.x, w1.y, w2.x, w2.y};
            #pragma unroll
            for (int i = 0; i < 4; ++i)
                #pragma unroll
                for (int e = 0; e < 6; ++e)
                    acc[i][e] = fmaf(avv[i], wvv[e], acc[i][e]);
        }
    }

    __syncthreads();
    if (kg == 1) {                        // publish K-half-1 partial sums
        #pragma unroll
        for (int i = 0; i < 4; ++i)
            #pragma unroll
            for (int e = 0; e < 6; ++e) ACCX[ttid][i * 6 + e] = acc[i][e];
    }
    __syncthreads();
    if (kg == 0) {                        // combine + bias + store
        float bias[6];
        #pragma unroll
        for (int e = 0; e < 6; ++e) {
            const int cl = cg * 6 + e;    // c % 96
            const int c  = col0 + cl;
            bias[e] = bih[c] + (cl < 64 ? bhh[c] : 0.f);
        }
        #pragma unroll
        for (int i = 0; i < 4; ++i) {
            const size_t base = (size_t)(row0 + rg * 4 + i) * NB_C + col0 + cg * 6;
            #pragma unroll
            for (int e = 0; e < 6; e += 2) {
                float2 o;
                o.x = acc[i][e]   + ACCX[ttid][i*6+e]   + bias[e];
                o.y = acc[i][e+1] + ACCX[ttid][i*6+e+1] + bias[e+1];
                *(float2*)&gi[base + e] = o;
            }
        }
    }
}

// ---------------------------------------------------------------------------
// Kernel 2: fused gh-GEMM + GRU + write-key logits + gumbel-argmax + gather.
// 256 blocks x 512 threads (VGPR-safe shape: r2/r3/r6 showed 1024-thr blocks
// always get squeezed to 64 VGPR and spill). Wave = one b; ALL 16 k's per
// pass, templates split across 2 passes (tq): acc[16][6] per pass.
// vs r4: P-LDS traffic halved (3 b64/mm once per tq-half instead of 2x3 b128)
// and HT broadcasts amortize over 16 k's. Logits cross passes via wave-local
// LDS LG (in-order DS pipe -> no barrier). hn kept in two named arrays
// (hn0/hn1) so all indexing is compile-time (no scratch).
// ---------------------------------------------------------------------------
__global__ __launch_bounds__(512, 2)
void k2_fused(const float* __restrict__ h,      const float* __restrict__ Whh,
              const float* __restrict__ bhh,    const float* __restrict__ wread,
              const float* __restrict__ wwrite, const float* __restrict__ gumb,
              const float* __restrict__ gi,     float* __restrict__ out)
{
    __shared__ __align__(16) float P2[2][3][32][128];  // 96 KB  Whh (tq,gc,mm,slot*2+u)
    __shared__ __align__(16) float WWT2[2][16][128];   // 16 KB
    __shared__ __align__(16) float WR[512];            //  2 KB  w_read [m][f]
    __shared__ __align__(16) float HT[8][32][20];      // 20 KB  [bl][m][k]
    __shared__ __align__(16) float HR2T[8][16][20];    // 10 KB  [bl][f][k]
    __shared__ __align__(16) float LG[8][16][8];       //  4 KB  [bl][k][t]

    const int tid  = threadIdx.x;
    const int wave = tid >> 6, lane = tid & 63;
    const int bl   = wave;
    const int b    = blockIdx.x * 8 + bl;
    const int m_   = lane & 31, half = lane >> 5;

    // ---- stage Whh: (t,gc,mout,mm) -> [t>>2][gc][mm][slot*2 + (t&1)],
    //      slot = (((t>>1)&1)*32 + mout) ^ mm  (reads land at lane^mm: 2-way)
    for (int i = tid; i < 24576; i += 512) {
        const int c = i >> 5, mm = i & 31;
        const int t = c / 96, rem = c - t * 96;
        const int gc = rem >> 5, mout = rem & 31;
        const int slot = (((t >> 1) & 1) * 32 + mout) ^ mm;
        P2[t >> 2][gc][mm][slot * 2 + (t & 1)] = Whh[i];
    }
    for (int i = tid; i < 4096; i += 512) {     // wwrite flat [t][m][f]
        const int t = i >> 9, mo = (i >> 4) & 31, f = i & 15;
        WWT2[t >> 2][f][(((t >> 1) & 1) * 32 + mo) * 2 + (t & 1)] = wwrite[i];
    }
    if (tid < 512) WR[tid] = wread[tid];
    #pragma unroll
    for (int e = 0; e < 8; ++e) {               // h row transposed: HT[m][k]
        const int idx = e * 64 + lane;
        HT[bl][idx & 31][idx >> 5] = h[(size_t)b * NB_NHID + idx];
    }
    __syncthreads();

    // ---- h_read (wave-local): lane owns (k = lane>>2, f-quad = (lane&3)*4)
    {
        const int kq = lane >> 2;
        const int f0 = (lane & 3) * 4;
        float s0 = 0.f, s1 = 0.f, s2 = 0.f, s3 = 0.f;
        #pragma unroll 8
        for (int mm = 0; mm < 32; ++mm) {
            const float  hv = HT[bl][mm][kq];
            const float4 wr = *(const float4*)&WR[mm * 16 + f0];
            s0 = fmaf(hv, wr.x, s0); s1 = fmaf(hv, wr.y, s1);
            s2 = fmaf(hv, wr.z, s2); s3 = fmaf(hv, wr.w, s3);
        }
        HR2T[bl][f0    ][lane >> 2] = s0;
        HR2T[bl][f0 + 1][lane >> 2] = s1;
        HR2T[bl][f0 + 2][lane >> 2] = s2;
        HR2T[bl][f0 + 3][lane >> 2] = s3;
    }

    float hn0[16][2], hn1[16][2];   // hnext for this lane's templates, pass 0/1

    auto do_pass = [&](const int tq, float (&hnP)[16][2]) {
        // ---- gh GEMM: acc[k][u*3+gc], one streaming pass over the tq-half
        float acc[16][6];
        #pragma unroll
        for (int k = 0; k < 16; ++k)
            #pragma unroll
            for (int j = 0; j < 6; ++j) acc[k][j] = 0.f;

        #pragma unroll 2
        for (int mm = 0; mm < 32; ++mm) {
            const int sl2 = (lane ^ mm) * 2;
            const float2 w0 = *(const float2*)&P2[tq][0][mm][sl2];
            const float2 w1 = *(const float2*)&P2[tq][1][mm][sl2];
            const float2 w2 = *(const float2*)&P2[tq][2][mm][sl2];
            const float4 ha = *(const float4*)&HT[bl][mm][0];    // broadcast
            const float4 hb = *(const float4*)&HT[bl][mm][4];
            const float4 hc = *(const float4*)&HT[bl][mm][8];
            const float4 hd = *(const float4*)&HT[bl][mm][12];
            const float hr[16] = {ha.x,ha.y,ha.z,ha.w, hb.x,hb.y,hb.z,hb.w,
                                  hc.x,hc.y,hc.z,hc.w, hd.x,hd.y,hd.z,hd.w};
            #pragma unroll
            for (int k = 0; k < 16; ++k) {
                acc[k][0] = fmaf(hr[k], w0.x, acc[k][0]);
                acc[k][1] = fmaf(hr[k], w1.x, acc[k][1]);
                acc[k][2] = fmaf(hr[k], w2.x, acc[k][2]);
                acc[k][3] = fmaf(hr[k], w0.y, acc[k][3]);
                acc[k][4] = fmaf(hr[k], w1.y, acc[k][4]);
                acc[k][5] = fmaf(hr[k], w2.y, acc[k][5]);
            }
        }

        // ---- write-key dot ww[k][u] = sum_f w_write[t][m_][f] * h_read[k][f]
        float ww[16][2];
        #pragma unroll
        for (int k = 0; k < 16; ++k) { ww[k][0] = 0.f; ww[k][1] = 0.f; }
        #pragma unroll 4
        for (int f = 0; f < 16; ++f) {
            const float2 wt = *(const float2*)&WWT2[tq][f][lane * 2];
            const float4 ka = *(const float4*)&HR2T[bl][f][0];   // broadcast
            const float4 kb = *(const float4*)&HR2T[bl][f][4];
            const float4 kc = *(const float4*)&HR2T[bl][f][8];
            const float4 kd = *(const float4*)&HR2T[bl][f][12];
            const float hk[16] = {ka.x,ka.y,ka.z,ka.w, kb.x,kb.y,kb.z,kb.w,
                                  kc.x,kc.y,kc.z,kc.w, kd.x,kd.y,kd.z,kd.w};
            #pragma unroll
            for (int k = 0; k < 16; ++k) {
                ww[k][0] = fmaf(hk[k], wt.x, ww[k][0]);
                ww[k][1] = fmaf(hk[k], wt.y, ww[k][1]);
            }
        }

        // ---- per-lane gi' (bih+bhh_{r,z} folded by k1) and bhh_n
        float gi_r[2][3], bhn[2];
        #pragma unroll
        for (int u = 0; u < 2; ++u) {
            const int t = tq * 4 + half * 2 + u;
            #pragma unroll
            for (int gc = 0; gc < 3; ++gc)
                gi_r[u][gc] = gi[(size_t)b * NB_C + t * 96 + gc * 32 + m_];
            bhn[u] = bhh[t * 96 + 64 + m_];
        }

        // ---- gates + logit partials for this pass's 2 templates x 16 k
        #pragma unroll
        for (int k = 0; k < 16; ++k) {
            const float h2v = HT[bl][m_][k];
            #pragma unroll
            for (int u = 0; u < 2; ++u) {
                const float xr = gi_r[u][0] + acc[k][u*3+0];
                const float xz = gi_r[u][1] + acc[k][u*3+1];
                const float gn = bhn[u]     + acc[k][u*3+2];
                const float rg = 1.f / (1.f + __expf(-xr));
                const float zg = 1.f / (1.f + __expf(-xz));
                const float xn = gi_r[u][2] + rg * gn;
                const float e2 = __expf(2.f * xn);
                const float tn = 1.f - 2.f / (e2 + 1.f);     // tanh
                const float hv2 = (1.f - zg) * tn + zg * h2v;
                hnP[k][u] = hv2;
                float part = hv2 * ww[k][u];                 // logit partial
                part += __shfl_xor(part, 1, 64);
                part += __shfl_xor(part, 2, 64);
                part += __shfl_xor(part, 4, 64);
                part += __shfl_xor(part, 8, 64);
                part += __shfl_xor(part, 16, 64);
                if (m_ == 0)                                 // lanes 0 and 32
                    LG[bl][k][tq * 4 + half * 2 + u] = part;
            }
        }
    };

    do_pass(0, hn0);
    do_pass(1, hn1);
    // LG writes/reads are same-wave DS ops -> in order, no barrier needed.

    // ---- final: gumbel-argmax, gather + one-hot
    #pragma unroll
    for (int k = 0; k < 16; ++k) {
        const float4 l0 = *(const float4*)&LG[bl][k][0];     // broadcast
        const float4 l1 = *(const float4*)&LG[bl][k][4];
        const float* gp = gumb + ((size_t)b * NB_K + k) * NB_T;
        const float4 g0 = *(const float4*)gp;
        const float4 g1 = *(const float4*)(gp + 4);
        const float s[8] = {l0.x+g0.x, l0.y+g0.y, l0.z+g0.z, l0.w+g0.w,
                            l1.x+g1.x, l1.y+g1.y, l1.z+g1.z, l1.w+g1.w};
        float best = s[0]; int bt = 0;
        #pragma unroll
        for (int t2 = 1; t2 < 8; ++t2)
            if (s[t2] > best) { best = s[t2]; bt = t2; }     // first-max argmax
        const int pq = bt >> 2, hf = (bt >> 1) & 1, hu = bt & 1;
        const float v0 = pq ? hn1[k][0] : hn0[k][0];
        const float v1 = pq ? hn1[k][1] : hn0[k][1];
        const float hsel = hu ? v1 : v0;
        if (half == hf)
            out[(size_t)b * NB_NHID + k * 32 + m_] = hsel;
        if (lane < 8)
            out[H_OUT_ELEMS + ((size_t)b * NB_K + k) * NB_T + lane] =
                (lane == bt) ? 1.f : 0.f;
    }
}

extern "C" void kernel_launch(void* const* d_in, const int* in_sizes, int n_in,
                              void* d_out, int out_size, void* d_ws, size_t ws_size,
                              hipStream_t stream) {
    const float* x      = (const float*)d_in[0];
    const float* h      = (const float*)d_in[1];
    const float* Wih    = (const float*)d_in[2];
    const float* Whh    = (const float*)d_in[3];
    const float* bih    = (const float*)d_in[4];
    const float* bhh    = (const float*)d_in[5];
    const float* wread  = (const float*)d_in[6];
    const float* wwrite = (const float*)d_in[7];
    const float* gumb   = (const float*)d_in[8];
    float* out = (float*)d_out;
    float* gi  = (float*)d_ws;   // 2048*768*4 = 6 MB scratch

    k1_gemm_gi<<<dim3(32, 8), 512, 0, stream>>>(x, Wih, bih, bhh, gi);
    k2_fused<<<dim3(256), 512, 0, stream>>>(h, Whh, bhh, wread, wwrite,
                                            gumb, gi, out);
}

// Round 8
// 87.469 us; speedup vs baseline: 1.1914x; 1.0531x over previous
//
#include <hip/hip_runtime.h>

#define NB_BS   2048
#define NB_NINP 512
#define NB_NHID 512
#define NB_K    16
#define NB_T    8
#define NB_M    32
#define NB_C    768   // T * 3 * M
#define H_OUT_ELEMS (NB_BS * NB_NHID)   // 1048576

// ---------------------------------------------------------------------------
// Kernel 1: gi'[b][c] = sum_i x[b][i]*Wih[c][i] + bih[c] + (gate<2 ? bhh[c] : 0)
// 64x96 tile, 1024 threads (16 waves = 4 waves/SIMD -- r7-k1 ran 2 and was
// latency-bound at 26us vs 10.2us VALU + ~9us DS floors). Intra-block K-split:
// kg=0 -> K 0..255, kg=1 -> K 256..511; combine via ACCX in LDS.
// Micro 4x3 with STRIDED cols (cg, cg+32, cg+64): wv = 3x b32, 32 distinct
// addrs over half-wave = conflict-free; av = b128 at 2 addrs (bc-cheap).
// Grid (32,8) = 256 = 1 block/CU balanced. LDS 69.6 KB.
// ---------------------------------------------------------------------------
__global__ __launch_bounds__(1024)
void k1_gemm_gi(const float* __restrict__ x, const float* __restrict__ Wih,
                const float* __restrict__ bih, const float* __restrict__ bhh,
                float* __restrict__ gi)
{
    __shared__ __align__(16) float As[2][32][68];    // [kg][k][row] 17.4 KB
    __shared__ __align__(16) float Bs[2][32][100];   // [kg][k][col] 25.6 KB
    __shared__ float ACCX[512][13];                  // 26.6 KB

    const int tid  = threadIdx.x;
    const int kg   = tid >> 9;            // K-half
    const int ttid = tid & 511;
    const int row0 = blockIdx.x * 64;
    const int col0 = blockIdx.y * 96;
    const int rg   = ttid >> 5;           // 0..15 -> rows rg*4..+3
    const int cg   = ttid & 31;           // cols cg + {0,32,64}
    const int kb0  = kg * 256;

    // A staging: 512 f4 = 64 rows x 8 k-quads (1/thread of this kg)
    const int ar = ttid >> 3, akq = (ttid & 7) * 4;
    // B staging: 768 f4 = 96 cols x 8 k-quads (1.5/thread: 2nd round ttid<256)
    const int bc0 = ttid >> 3,        bkq0 = (ttid & 7) * 4;
    const int bc1 = 64 + (ttid >> 3), bkq1 = (ttid & 7) * 4;   // ttid<256 only

    float4 a0 = *(const float4*)&x[(size_t)(row0 + ar) * NB_NINP + kb0 + akq];
    float4 b0 = *(const float4*)&Wih[(size_t)(col0 + bc0) * NB_NINP + kb0 + bkq0];
    float4 b1;
    if (ttid < 256)
        b1 = *(const float4*)&Wih[(size_t)(col0 + bc1) * NB_NINP + kb0 + bkq1];

    float acc[4][3];
    #pragma unroll
    for (int i = 0; i < 4; ++i)
        #pragma unroll
        for (int e = 0; e < 3; ++e) acc[i][e] = 0.f;

    for (int slab = 0; slab < 8; ++slab) {
        __syncthreads();
        As[kg][akq+0][ar]=a0.x; As[kg][akq+1][ar]=a0.y;
        As[kg][akq+2][ar]=a0.z; As[kg][akq+3][ar]=a0.w;
        Bs[kg][bkq0+0][bc0]=b0.x; Bs[kg][bkq0+1][bc0]=b0.y;
        Bs[kg][bkq0+2][bc0]=b0.z; Bs[kg][bkq0+3][bc0]=b0.w;
        if (ttid < 256) {
            Bs[kg][bkq1+0][bc1]=b1.x; Bs[kg][bkq1+1][bc1]=b1.y;
            Bs[kg][bkq1+2][bc1]=b1.z; Bs[kg][bkq1+3][bc1]=b1.w;
        }
        __syncthreads();
        if (slab < 7) {   // prefetch next slab of this K-half
            const int kb = kb0 + (slab + 1) * 32;
            a0 = *(const float4*)&x[(size_t)(row0 + ar) * NB_NINP + kb + akq];
            b0 = *(const float4*)&Wih[(size_t)(col0 + bc0) * NB_NINP + kb + bkq0];
            if (ttid < 256)
                b1 = *(const float4*)&Wih[(size_t)(col0 + bc1) * NB_NINP + kb + bkq1];
        }
        #pragma unroll
        for (int kk = 0; kk < 32; ++kk) {
            const float4 av = *(const float4*)&As[kg][kk][rg * 4];
            const float w0 = Bs[kg][kk][cg];
            const float w1 = Bs[kg][kk][cg + 32];
            const float w2 = Bs[kg][kk][cg + 64];
            const float avv[4] = {av.x, av.y, av.z, av.w};
            #pragma unroll
            for (int i = 0; i < 4; ++i) {
                acc[i][0] = fmaf(avv[i], w0, acc[i][0]);
                acc[i][1] = fmaf(avv[i], w1, acc[i][1]);
                acc[i][2] = fmaf(avv[i], w2, acc[i][2]);
            }
        }
    }

    __syncthreads();
    if (kg == 1) {                        // publish K-half-1 partials
        #pragma unroll
        for (int i = 0; i < 4; ++i)
            #pragma unroll
            for (int e = 0; e < 3; ++e) ACCX[ttid][i * 3 + e] = acc[i][e];
    }
    __syncthreads();
    if (kg == 0) {                        // combine + bias + store
        float bias[3];
        #pragma unroll
        for (int e = 0; e < 3; ++e) {
            const int c = col0 + cg + e * 32;      // cl = cg + e*32 < 64 <=> e<2
            bias[e] = bih[c] + (e < 2 ? bhh[c] : 0.f);
        }
        #pragma unroll
        for (int i = 0; i < 4; ++i) {
            const size_t base = (size_t)(row0 + rg * 4 + i) * NB_C + col0 + cg;
            #pragma unroll
            for (int e = 0; e < 3; ++e)
                gi[base + e * 32] = acc[i][e] + ACCX[ttid][i * 3 + e] + bias[e];
        }
    }
}

// ---------------------------------------------------------------------------
// Kernel 2: fused gh-GEMM + GRU + write-key logits + gumbel-argmax + gather.
// EXACT r5 structure (proven 54.7us / 60 VGPR / no spill): 256 blocks x 1024
// threads (16 waves = 4 waves/SIMD), waves_per_eu(4,4) spill guard.
// Wave (bl,kh): b = blockIdx*8+bl, k-half kh; 2 passes of 4 k's, acc[4][12].
// ONE change: WWT repacked as float4 WWT4[f][half*32+m_] (p-quad per slot) ->
// write-key loop reads 1 spread b128 instead of 4 scalar b32 per f
// (-48 DS ops/pass, ~15% of the DS-pipe load).
// ---------------------------------------------------------------------------
__global__ __launch_bounds__(1024)
__attribute__((amdgpu_waves_per_eu(4, 4)))
void k2_fused(const float* __restrict__ h,      const float* __restrict__ Whh,
              const float* __restrict__ bhh,    const float* __restrict__ wread,
              const float* __restrict__ wwrite, const float* __restrict__ gumb,
              const float* __restrict__ gi,     float* __restrict__ out)
{
    __shared__ __align__(16) float4 P[3][32][64];   // 98304 B  W_hh planes
    __shared__ __align__(16) float4 WWT4[16][64];   // 16384 B  [f][half*32+m]:p-quad
    __shared__ __align__(16) float WR[512];         //  2048 B  w_read [m][f]
    __shared__ __align__(16) float HT[8][32][20];   // 20480 B  [bl][m][k]
    __shared__ __align__(16) float HR2T[8][16][20]; // 10240 B  [bl][f][k]

    const int tid  = threadIdx.x;
    const int wave = tid >> 6, lane = tid & 63;
    const int bl   = wave >> 1, kh = wave & 1;
    const int b    = blockIdx.x * 8 + bl;
    const int m_   = lane & 31, half = lane >> 5;

    // ---- stage W_hh planes (value for reading-lane sl at contraction mm
    //      lands at float4 slot sl ^ (mm&7) of row [j>>2][mm])
    float* PF = (float*)P;
    for (int i = tid; i < 24576; i += 1024) {       // Whh flat [c][m]; c=t*96+gc*32+mout
        const int c = i >> 5, mm = i & 31;
        const int t = c / 96, rem = c - t * 96;
        const int gc = rem >> 5, mout = rem & 31;
        const int j  = (t >> 1) * 3 + gc;
        const int sl = ((t & 1) * 32 + mout) ^ (mm & 7);
        PF[(((j >> 2) * 32 + mm) * 64 + sl) * 4 + (j & 3)] = Whh[i];
    }
    for (int i = tid; i < 4096; i += 1024) {        // wwrite flat [t][m][f]
        const int t = i >> 9, mo = (i >> 4) & 31, f = i & 15;
        ((float*)WWT4)[(f * 64 + (t & 1) * 32 + mo) * 4 + (t >> 1)] = wwrite[i];
    }
    if (tid < 512) WR[tid] = wread[tid];
    #pragma unroll
    for (int e = 0; e < 4; ++e) {                   // this wave's h half-row, transposed
        const int idx = kh * 256 + e * 64 + lane;
        HT[bl][idx & 31][idx >> 5] = h[(size_t)b * NB_NHID + idx];
    }
    __syncthreads();   // only barrier; everything below is wave-local

    // ---- h_read for this wave's 8 k's: lane owns (k = kh*8 + lane>>3, f-pair)
    {
        const int kq = kh * 8 + (lane >> 3);
        const int f0 = (lane & 7) * 2;
        float s0 = 0.f, s1 = 0.f;
        #pragma unroll 8
        for (int mm = 0; mm < 32; ++mm) {
            const float hv = HT[bl][mm][kq];
            s0 = fmaf(hv, WR[mm * 16 + f0], s0);
            s1 = fmaf(hv, WR[mm * 16 + f0 + 1], s1);
        }
        HR2T[bl][f0    ][kq] = s0;
        HR2T[bl][f0 + 1][kq] = s1;
    }

    // ---- per-lane gi' (bih+bhh_{r,z} folded by k1) and bhh_n
    float gi_r[4][3], bhn[4];
    #pragma unroll
    for (int p = 0; p < 4; ++p) {
        const int t = 2 * p + half;
        #pragma unroll
        for (int gc = 0; gc < 3; ++gc)
            gi_r[p][gc] = gi[(size_t)b * NB_C + t * 96 + gc * 32 + m_];
        bhn[p] = bhh[t * 96 + 64 + m_];
    }

    #pragma unroll 1
    for (int pass = 0; pass < 2; ++pass) {
        const int k0 = kh * 8 + pass * 4;

        // ---- gh GEMM, 4 k's: 48 FMA per mm; 3 spread b128 + 1 broadcast b128
        float acc[4][12];
        #pragma unroll
        for (int r = 0; r < 4; ++r)
            #pragma unroll
            for (int j = 0; j < 12; ++j) acc[r][j] = 0.f;

        #pragma unroll 4
        for (int mm = 0; mm < 32; ++mm) {
            const int sw = lane ^ (mm & 7);          // undo staging swizzle
            const float4 w0 = P[0][mm][sw];
            const float4 w1 = P[1][mm][sw];
            const float4 w2 = P[2][mm][sw];
            const float4 hv = *(const float4*)&HT[bl][mm][k0];   // broadcast
            const float wj[12] = {w0.x,w0.y,w0.z,w0.w, w1.x,w1.y,w1.z,w1.w,
                                  w2.x,w2.y,w2.z,w2.w};
            const float hr4[4] = {hv.x, hv.y, hv.z, hv.w};
            #pragma unroll
            for (int r = 0; r < 4; ++r)
                #pragma unroll
                for (int j = 0; j < 12; ++j)
                    acc[r][j] = fmaf(hr4[r], wj[j], acc[r][j]);
        }

        // ---- write-key dot ww[r][p] = sum_f w_write[t][m_][f] * h_read[k][f]
        float ww[4][4];
        #pragma unroll
        for (int r = 0; r < 4; ++r)
            #pragma unroll
            for (int p = 0; p < 4; ++p) ww[r][p] = 0.f;
        #pragma unroll 4
        for (int f = 0; f < 16; ++f) {
            const float4 wt4 = WWT4[f][half * 32 + m_];           // b128 spread
            const float4 hka = *(const float4*)&HR2T[bl][f][k0];  // broadcast
            const float wt[4] = {wt4.x, wt4.y, wt4.z, wt4.w};
            const float hk[4] = {hka.x, hka.y, hka.z, hka.w};
            #pragma unroll
            for (int r = 0; r < 4; ++r)
                #pragma unroll
                for (int p = 0; p < 4; ++p)
                    ww[r][p] = fmaf(hk[r], wt[p], ww[r][p]);
        }

        // ---- per-k epilogue: gates, logits, argmax, gather
        #pragma unroll
        for (int r = 0; r < 4; ++r) {
            const int k = k0 + r;
            const float h2v = HT[bl][m_][k];
            float hn[4], lg[4];
            #pragma unroll
            for (int p = 0; p < 4; ++p) {
                const float xr = gi_r[p][0] + acc[r][p*3+0];
                const float xz = gi_r[p][1] + acc[r][p*3+1];
                const float gn = bhn[p]     + acc[r][p*3+2];
                const float rg = 1.f / (1.f + __expf(-xr));
                const float zg = 1.f / (1.f + __expf(-xz));
                const float xn = gi_r[p][2] + rg * gn;
                const float e2 = __expf(2.f * xn);
                const float tn = 1.f - 2.f / (e2 + 1.f);   // tanh
                const float hv2 = (1.f - zg) * tn + zg * h2v;
                hn[p] = hv2;
                float part = hv2 * ww[r][p];               // logit partial
                part += __shfl_xor(part, 1, 64);
                part += __shfl_xor(part, 2, 64);
                part += __shfl_xor(part, 4, 64);
                part += __shfl_xor(part, 8, 64);
                part += __shfl_xor(part, 16, 64);
                lg[p] = part;
            }
            float s[8];
            #pragma unroll
            for (int p = 0; p < 4; ++p) {
                const float oth = __shfl_xor(lg[p], 32, 64);
                s[2*p]   = half ? oth   : lg[p];
                s[2*p+1] = half ? lg[p] : oth;
            }
            const float* gp = gumb + ((size_t)b * NB_K + k) * NB_T;
            const float4 ga = *(const float4*)gp;
            const float4 gb = *(const float4*)(gp + 4);
            const float gv[8] = {ga.x,ga.y,ga.z,ga.w, gb.x,gb.y,gb.z,gb.w};
            float best = s[0] + gv[0]; int bt = 0;
            #pragma unroll
            for (int t2 = 1; t2 < 8; ++t2) {
                const float v = s[t2] + gv[t2];
                if (v > best) { best = v; bt = t2; }   // first-max argmax
            }
            const int pstar = bt >> 1, hstar = bt & 1;
            float hsel = hn[0];
            hsel = (pstar == 1) ? hn[1] : hsel;
            hsel = (pstar == 2) ? hn[2] : hsel;
            hsel = (pstar == 3) ? hn[3] : hsel;
            if (half == hstar)
                out[(size_t)b * NB_NHID + k * 32 + m_] = hsel;
            if (lane < 8)
                out[H_OUT_ELEMS + ((size_t)b * NB_K + k) * NB_T + lane] =
                    (lane == bt) ? 1.f : 0.f;
        }
    }
}

extern "C" void kernel_launch(void* const* d_in, const int* in_sizes, int n_in,
                              void* d_out, int out_size, void* d_ws, size_t ws_size,
                              hipStream_t stream) {
    const float* x      = (const float*)d_in[0];
    const float* h      = (const float*)d_in[1];
    const float* Wih    = (const float*)d_in[2];
    const float* Whh    = (const float*)d_in[3];
    const float* bih    = (const float*)d_in[4];
    const float* bhh    = (const float*)d_in[5];
    const float* wread  = (const float*)d_in[6];
    const float* wwrite = (const float*)d_in[7];
    const float* gumb   = (const float*)d_in[8];
    float* out = (float*)d_out;
    float* gi  = (float*)d_ws;   // 2048*768*4 = 6 MB scratch

    k1_gemm_gi<<<dim3(32, 8), 1024, 0, stream>>>(x, Wih, bih, bhh, gi);
    k2_fused<<<dim3(256), 1024, 0, stream>>>(h, Whh, bhh, wread, wwrite,
                                             gumb, gi, out);
}